// Round 4
// baseline (192.151 us; speedup 1.0000x reference)
//
#include <hip/hip_runtime.h>

typedef unsigned short u16;
typedef unsigned int u32;
typedef __attribute__((ext_vector_type(8))) short short8;
typedef __attribute__((ext_vector_type(4))) float floatx4;
typedef __attribute__((ext_vector_type(4))) float float4v;

#define B_ 32
#define T_ 168
#define NH_ 32
#define NM_ 64
#define E_ 384
#define HL_ 128
#define FUT_ 24
#define SLOPE_ 0.01f
#define XP_ 80     // xbuf stride per batch (u16)
#define HP_ 144    // hbuf stride per batch (u16)
#define WIH_LP 72  // Wih staging row stride (u16): 512*72 = 36864 u16 fits ovl
#define WHH_LP 136 // Whh staging row stride (u16): 256*136 = 34816 u16 fits ovl
#define OVL_E (T_ * 4 * XP_)  // 53760 u16 = 107.5 KB

// gate scales folded into the staged weights/bias:
//   sigm(x) = rcp(1 + exp2(-log2e * x))  -> rows i,f,o pre-scaled by -log2e
//   tanh(x) = 1 - 2*rcp(1 + exp2(2*log2e * x)) -> rows g pre-scaled by +2*log2e
#define NS1_ (-1.4426950408889634f)
#define S2_ (2.8853900817779268f)

static __device__ __forceinline__ float b2f(u16 u) {
  u32 v = ((u32)u) << 16;
  return __builtin_bit_cast(float, v);
}
static __device__ __forceinline__ u16 f2bf(float f) {
  u32 x = __builtin_bit_cast(u32, f);
  u32 r = (x + 0x7fffu + ((x >> 16) & 1u)) >> 16;
  return (u16)r;
}
static __device__ __forceinline__ float fexp2(float x) { return __builtin_amdgcn_exp2f(x); }
static __device__ __forceinline__ float frcp(float x) { return __builtin_amdgcn_rcpf(x); }
static __device__ __forceinline__ float sel4(floatx4 v, int r) {
  float m0 = (r & 1) ? v[1] : v[0];
  float m1 = (r & 1) ? v[3] : v[2];
  return (r & 2) ? m1 : m0;
}
static __device__ __forceinline__ float lrelu(float x) { return fmaxf(x, SLOPE_ * x); }

// Fully fused GNN + per-station LSTM + head.
// Grid: 256 WGs = 32 stations x 8 batch-groups (4 batches). 512 thr = 8 waves.
__launch_bounds__(512, 2)
__global__ void fused_kernel(const float* __restrict__ dm, const float* __restrict__ dh,
                             const int* __restrict__ eidx,
                             const float* __restrict__ Wroot, const float* __restrict__ Wrel,
                             const float* __restrict__ bgnn,
                             const float* __restrict__ Wih, const float* __restrict__ Whh,
                             const float* __restrict__ bih, const float* __restrict__ bhh,
                             const float* __restrict__ Wlin, const float* __restrict__ blin,
                             float* __restrict__ out) {
  const int s = blockIdx.x & 31;
  const int bg = blockIdx.x >> 5;
  const int tid = threadIdx.x;
  const int w = tid >> 6;
  const int lane = tid & 63;
  const int cm = lane & 15;
  const int q = lane >> 4;
  const int b = cm & 3;
  const int rho = cm >> 2;

  // ovl: weight staging rounds first, then xbuf (GNN features)
  __shared__ __align__(16) u16 ovl[OVL_E];
  __shared__ __align__(16) u16 hbuf[2 * 4 * HP_];
  // xg: wave-private x-gate staging. Per-wave layout (floats):
  //   F = uf*256 + q*64 + b*16 + ((blk^q)&3)*4 + j     (j = gate sub-row)
  // Write (b128, fixed blk): start pos = 16(b&1)+4((blk^q)&3) -> 8 slots tiling
  // 32 banks, 8 lanes/slot = b128 minimum -> conflict-free.
  // Read (b32, fixed u,blk): pos = 16(b&1)+4((blk^q)&3)+rho -> 2-way (free).
  // Single-buffered is safe: pieces for group tt+1 are held in REGISTERS during
  // group tt and written at the top of iteration tt+1, after all of group tt's
  // reads (same wave, program order, in-order DS pipe).
  __shared__ __align__(16) float xgbuf[8 * 1024];  // 32 KB
  __shared__ float xh_lds[4][T_];
  __shared__ float ag_lds[4][T_];
  __shared__ float wr_s[64], wv_s[64], bg_s[64];
  __shared__ int srcs[E_];
  __shared__ int nsrc, iflag;

  // ---- A: init
  if (tid == 0) { nsrc = 0; iflag = 0; }
  for (int i = tid; i < 2 * 4 * HP_; i += 512) hbuf[i] = 0;
  __syncthreads();

  // ---- B: int64-vs-int32 edge_index probe
  {
    int odd = 0;
    for (int e = tid; e < E_; e += 512) odd |= eidx[2 * e + 1];
    if (odd) atomicOr(&iflag, 1);
  }
  __syncthreads();
  const bool i32 = iflag != 0;

  // ---- C: in-edges for this station; stage small tensors; bias (pre-scaled)
  for (int e = tid; e < E_; e += 512) {
    int se = i32 ? eidx[e] : eidx[2 * e];
    int de = i32 ? eidx[E_ + e] : eidx[2 * E_ + 2 * e];
    if (de == s) { int i = atomicAdd(&nsrc, 1); srcs[i] = se; }
  }
  if (tid < 64) { wr_s[tid] = Wroot[tid]; wv_s[tid] = Wrel[tid]; bg_s[tid] = bgnn[tid]; }
  for (int i = tid; i < 4 * T_; i += 512) {
    int bb = i / T_, t = i % T_;
    xh_lds[bb][t] = dh[((size_t)(bg * 4 + bb) * T_ + t) * NH_ + s];
  }
  floatx4 bias_init[4];
#pragma unroll
  for (int blk = 0; blk < 4; blk++) {
    const float scb = (blk == 2) ? S2_ : NS1_;
#pragma unroll
    for (int r = 0; r < 4; r++) {
      const int nb = blk * 128 + w * 16 + q * 4 + r;
      bias_init[blk][r] = (bih[s * 512 + nb] + bhh[s * 512 + nb]) * scb;
    }
  }
  __syncthreads();

  // ---- D: per-(b,t) graph aggregation (avg ~4 in-edges/station)
  const int ns = nsrc;
  for (int i = tid; i < 4 * T_; i += 512) {
    int bb = i / T_, t = i % T_;
    size_t gb = (size_t)(bg * 4 + bb) * T_ + t;
    float a = 0.f;
    for (int j = 0; j < ns; j++) {
      int sr = srcs[j];
      a += (sr < NH_) ? dh[gb * NH_ + sr] : dm[gb * NM_ + (sr - NH_)];
    }
    ag_lds[bb][t] = a;
  }

  // ---- W: coalesced LDS-staged weight load, THREE fully-unrolled rounds.
  // Gate-scale constants are folded in here (off the recurrent critical path).
  short8 Af[4][6];
  const int nl = w * 16 + cm;  // this lane's gate-row within a 128-block
  // Round 1: all of Wih (512 rows x 64); row = j>>4, gate block = j>>11
  __syncthreads();
  {
    const float* g = Wih + (size_t)s * 512 * 64;
#pragma unroll
    for (int it = 0; it < 16; it++) {
      int j = tid + it * 512;
      float4v v = *(const float4v*)(g + 4 * j);
      const float sc = ((j >> 11) == 2) ? S2_ : NS1_;
      u16* dst = ovl + (j >> 4) * WIH_LP + (j & 15) * 4;
      dst[0] = f2bf(v[0] * sc); dst[1] = f2bf(v[1] * sc);
      dst[2] = f2bf(v[2] * sc); dst[3] = f2bf(v[3] * sc);
    }
  }
  __syncthreads();
#pragma unroll
  for (int blk = 0; blk < 4; blk++)
#pragma unroll
    for (int kk = 0; kk < 2; kk++)
      Af[blk][kk] = *(const short8*)(ovl + (blk * 128 + nl) * WIH_LP + kk * 32 + q * 8);
  __syncthreads();
  // Round 2: Whh rows 0..255 (gate blocks 0,1 -> always -log2e)
  {
    const float* g = Whh + (size_t)s * 512 * 128;
#pragma unroll
    for (int it = 0; it < 16; it++) {
      int j = tid + it * 512;
      float4v v = *(const float4v*)(g + 4 * j);
      u16* dst = ovl + (j >> 5) * WHH_LP + (j & 31) * 4;
      dst[0] = f2bf(v[0] * NS1_); dst[1] = f2bf(v[1] * NS1_);
      dst[2] = f2bf(v[2] * NS1_); dst[3] = f2bf(v[3] * NS1_);
    }
  }
  __syncthreads();
#pragma unroll
  for (int blk = 0; blk < 2; blk++)
#pragma unroll
    for (int kk = 0; kk < 4; kk++)
      Af[blk][2 + kk] = *(const short8*)(ovl + (blk * 128 + nl) * WHH_LP + kk * 32 + q * 8);
  __syncthreads();
  // Round 3: Whh rows 256..511 (block 2 = g -> +2log2e for j<4096, block 3 = o -> -log2e)
  {
    const float* g = Whh + ((size_t)s * 512 + 256) * 128;
#pragma unroll
    for (int it = 0; it < 16; it++) {
      int j = tid + it * 512;
      float4v v = *(const float4v*)(g + 4 * j);
      const float sc = (j < 4096) ? S2_ : NS1_;
      u16* dst = ovl + (j >> 5) * WHH_LP + (j & 31) * 4;
      dst[0] = f2bf(v[0] * sc); dst[1] = f2bf(v[1] * sc);
      dst[2] = f2bf(v[2] * sc); dst[3] = f2bf(v[3] * sc);
    }
  }
  __syncthreads();
#pragma unroll
  for (int blk = 2; blk < 4; blk++)
#pragma unroll
    for (int kk = 0; kk < 4; kk++)
      Af[blk][2 + kk] = *(const short8*)(ovl + ((blk - 2) * 128 + nl) * WHH_LP + kk * 32 + q * 8);
  __syncthreads();

  // ---- E: precompute GNN features into xbuf (= ovl; weights now in registers)
  {
    const int k = tid & 63;
    const int bb = (tid >> 6) & 3;
    const int th = tid >> 8;
    const float wrk = wr_s[k], wvk = wv_s[k], bgk = bg_s[k];
    for (int i = 0; i < T_ / 2; i++) {
      const int t = th * (T_ / 2) + i;
      const float xv = xh_lds[bb][t] * wrk + ag_lds[bb][t] * wvk + bgk;
      ovl[t * (4 * XP_) + bb * XP_ + k] = f2bf(lrelu(xv));
    }
  }
  __syncthreads();

  // ---- xg addressing (all loop-invariant; zero per-step address VALU)
  int boff[4];
#pragma unroll
  for (int k = 0; k < 4; k++) boff[k] = ((k ^ q) & 3) * 4;
  float* const xgW = xgbuf + w * 1024 + rho * 256 + q * 64 + b * 16;  // producer (uf = rho)
  const float* const xgR = xgbuf + w * 1024 + q * 64 + b * 16 + rho;  // consumer (+u*256+boff)

  floatx4 zvec;
  zvec[0] = 0.f; zvec[1] = 0.f; zvec[2] = 0.f; zvec[3] = 0.f;

  // ---- prologue: compute x-gate pieces for group 0 into registers (tb = rho)
  floatx4 pax[4];
  {
    short8 Bx0 = *(const short8*)(ovl + rho * (4 * XP_) + b * XP_ + q * 8);
    short8 Bx1 = *(const short8*)(ovl + rho * (4 * XP_) + b * XP_ + 32 + q * 8);
#pragma unroll
    for (int k = 0; k < 4; k++) {
      pax[k] = __builtin_amdgcn_mfma_f32_16x16x32_bf16(Af[k][0], Bx0, bias_init[k], 0, 0, 0);
      pax[k] = __builtin_amdgcn_mfma_f32_16x16x32_bf16(Af[k][1], Bx1, pax[k], 0, 0, 0);
    }
  }

  // ---- recurrent loop. Per group: publish the register-held pieces, then 4
  // steps. Per step (post-barrier): issue Bh + xg reads, compute ONE burst
  // piece (2 MFMAs, depends only on Bn regs) to fill the ds_read window, then
  // h-MFMA chains (g,i first -> early exp2; then f,o), activation, barrier.
  float c = 0.0f;
  for (int tt = 0; tt < T_ / 4; tt++) {
    // publish group tt's x-gates (pieces computed during group tt-1 / prologue)
#pragma unroll
    for (int k = 0; k < 4; k++) *(floatx4*)(xgW + boff[k]) = pax[k];

    short8 Bn0, Bn1;
    {
      const int tbn = min((tt + 1) * 4, T_ - 4) + rho;  // clamp: last group's pieces unused
      Bn0 = *(const short8*)(ovl + tbn * (4 * XP_) + b * XP_ + q * 8);
      Bn1 = *(const short8*)(ovl + tbn * (4 * XP_) + b * XP_ + 32 + q * 8);
    }
#pragma unroll
    for (int u = 0; u < 4; u++) {
      const int p = u & 1, pn = p ^ 1;  // t = tt*4+u -> t&1 == u&1
      short8 Bh[4];
#pragma unroll
      for (int kk = 0; kk < 4; kk++)
        Bh[kk] = *(const short8*)(hbuf + p * (4 * HP_) + b * HP_ + kk * 32 + q * 8);
      // this lane's x+bias gate values for step tt*4+u
      const float xg0 = xgR[u * 256 + boff[0]];
      const float xg1 = xgR[u * 256 + boff[1]];
      const float xg2 = xgR[u * 256 + boff[2]];
      const float xg3 = xgR[u * 256 + boff[3]];

      // burst piece blk=u for group tt+1: registers only, fills the read window
      pax[u] = __builtin_amdgcn_mfma_f32_16x16x32_bf16(Af[u][0], Bn0, bias_init[u], 0, 0, 0);
      pax[u] = __builtin_amdgcn_mfma_f32_16x16x32_bf16(Af[u][1], Bn1, pax[u], 0, 0, 0);

      // g (blk2) and i (blk0) chains first -> their transcendentals start early
      floatx4 a2 = __builtin_amdgcn_mfma_f32_16x16x32_bf16(Af[2][2], Bh[0], zvec, 0, 0, 0);
      floatx4 a0 = __builtin_amdgcn_mfma_f32_16x16x32_bf16(Af[0][2], Bh[0], zvec, 0, 0, 0);
#pragma unroll
      for (int kk = 1; kk < 4; kk++) {
        a2 = __builtin_amdgcn_mfma_f32_16x16x32_bf16(Af[2][2 + kk], Bh[kk], a2, 0, 0, 0);
        a0 = __builtin_amdgcn_mfma_f32_16x16x32_bf16(Af[0][2 + kk], Bh[kk], a0, 0, 0, 0);
      }
      const float gg = sel4(a2, rho) + xg2;  // = 2*log2e * g
      const float gi = sel4(a0, rho) + xg0;  // = -log2e * i
      const float Eg = fexp2(gg);
      const float Ei = fexp2(gi);

      // f (blk1) and o (blk3) chains
      floatx4 a1 = __builtin_amdgcn_mfma_f32_16x16x32_bf16(Af[1][2], Bh[0], zvec, 0, 0, 0);
      floatx4 a3 = __builtin_amdgcn_mfma_f32_16x16x32_bf16(Af[3][2], Bh[0], zvec, 0, 0, 0);
#pragma unroll
      for (int kk = 1; kk < 4; kk++) {
        a1 = __builtin_amdgcn_mfma_f32_16x16x32_bf16(Af[1][2 + kk], Bh[kk], a1, 0, 0, 0);
        a3 = __builtin_amdgcn_mfma_f32_16x16x32_bf16(Af[3][2 + kk], Bh[kk], a3, 0, 0, 0);
      }

      const float tg = 1.0f - 2.0f * frcp(1.0f + Eg);
      const float si = frcp(1.0f + Ei);
      const float gf = sel4(a1, rho) + xg1;  // = -log2e * f
      const float go = sel4(a3, rho) + xg3;  // = -log2e * o
      const float sf = frcp(1.0f + fexp2(gf));
      c = sf * c + si * tg;
      const float tc = 1.0f - 2.0f * frcp(1.0f + fexp2(S2_ * c));
      const float so = frcp(1.0f + fexp2(go));
      const float hh = so * tc;
      u32 pk;
      asm("v_cvt_pk_bf16_f32 %0, %1, %2" : "=v"(pk) : "v"(hh), "v"(hh));
      hbuf[pn * (4 * HP_) + b * HP_ + w * 16 + q * 4 + rho] = (u16)pk;
      __syncthreads();
    }
  }

  // ---- head: final h is in hbuf[0]
  if (tid < 4 * FUT_) {
    const int bb = tid / FUT_;
    const int f = tid % FUT_;
    float a = blin[f];
#pragma unroll 8
    for (int k = 0; k < HL_; k++) a += b2f(hbuf[bb * HP_ + k]) * Wlin[f * HL_ + k];
    out[((size_t)(bg * 4 + bb) * NH_ + s) * FUT_ + f] = lrelu(a);
  }
}

extern "C" void kernel_launch(void* const* d_in, const int* in_sizes, int n_in,
                              void* d_out, int out_size, void* d_ws, size_t ws_size,
                              hipStream_t stream) {
  const float* dm = (const float*)d_in[0];
  const float* dh = (const float*)d_in[1];
  const int* eidx = (const int*)d_in[2];
  const float* Wroot = (const float*)d_in[3];
  const float* Wrel = (const float*)d_in[4];
  const float* bgnn = (const float*)d_in[5];
  const float* Wih = (const float*)d_in[6];
  const float* Whh = (const float*)d_in[7];
  const float* bih = (const float*)d_in[8];
  const float* bhh = (const float*)d_in[9];
  const float* Wlin = (const float*)d_in[10];
  const float* blin = (const float*)d_in[11];
  float* out = (float*)d_out;

  fused_kernel<<<256, 512, 0, stream>>>(dm, dh, eidx, Wroot, Wrel, bgnn, Wih, Whh,
                                        bih, bhh, Wlin, blin, out);
}

// Round 6
// 182.304 us; speedup vs baseline: 1.0540x; 1.0540x over previous
//
#include <hip/hip_runtime.h>

typedef unsigned short u16;
typedef unsigned int u32;
typedef __attribute__((ext_vector_type(8))) short short8;
typedef __attribute__((ext_vector_type(4))) float floatx4;
typedef __attribute__((ext_vector_type(4))) float float4v;

#define B_ 32
#define T_ 168
#define NH_ 32
#define NM_ 64
#define E_ 384
#define HL_ 128
#define FUT_ 24
#define SLOPE_ 0.01f
#define XP_ 80     // xbuf stride per batch (u16)
#define HP_ 144    // hbuf stride per batch (u16)
#define WIH_LP 72  // Wih staging row stride (u16): 512*72 = 36864 u16 fits ovl
#define WHH_LP 136 // Whh staging row stride (u16): 256*136 = 34816 u16 fits ovl
#define OVL_E (T_ * 4 * XP_)  // 53760 u16 = 107.5 KB

// gate scales folded into the staged weights/bias:
//   sigm(x) = rcp(1 + exp2(-log2e * x))  -> rows i,f,o pre-scaled by -log2e
//   tanh(x) = 1 - 2*rcp(1 + exp2(2*log2e * x)) -> rows g pre-scaled by +2*log2e
#define NS1_ (-1.4426950408889634f)
#define S2_ (2.8853900817779268f)

static __device__ __forceinline__ float b2f(u16 u) {
  u32 v = ((u32)u) << 16;
  return __builtin_bit_cast(float, v);
}
static __device__ __forceinline__ u16 f2bf(float f) {
  u32 x = __builtin_bit_cast(u32, f);
  u32 r = (x + 0x7fffu + ((x >> 16) & 1u)) >> 16;
  return (u16)r;
}
static __device__ __forceinline__ float fexp2(float x) { return __builtin_amdgcn_exp2f(x); }
static __device__ __forceinline__ float frcp(float x) { return __builtin_amdgcn_rcpf(x); }
static __device__ __forceinline__ float sel4(floatx4 v, int r) {
  float m0 = (r & 1) ? v[1] : v[0];
  float m1 = (r & 1) ? v[3] : v[2];
  return (r & 2) ? m1 : m0;
}
static __device__ __forceinline__ float lrelu(float x) { return fmaxf(x, SLOPE_ * x); }

// Fully fused GNN + per-station LSTM + head.
// Grid: 256 WGs = 32 stations x 8 batch-groups (4 batches). 512 thr = 8 waves.
__launch_bounds__(512, 2)
__global__ void fused_kernel(const float* __restrict__ dm, const float* __restrict__ dh,
                             const int* __restrict__ eidx,
                             const float* __restrict__ Wroot, const float* __restrict__ Wrel,
                             const float* __restrict__ bgnn,
                             const float* __restrict__ Wih, const float* __restrict__ Whh,
                             const float* __restrict__ bih, const float* __restrict__ bhh,
                             const float* __restrict__ Wlin, const float* __restrict__ blin,
                             float* __restrict__ out) {
  const int s = blockIdx.x & 31;
  const int bg = blockIdx.x >> 5;
  const int tid = threadIdx.x;
  const int w = tid >> 6;
  const int lane = tid & 63;
  const int cm = lane & 15;
  const int q = lane >> 4;
  const int b = cm & 3;
  const int rho = cm >> 2;

  // ovl: weight staging rounds first, then xbuf (GNN features)
  __shared__ __align__(16) u16 ovl[OVL_E];
  __shared__ __align__(16) u16 hbuf[2 * 4 * HP_];
  // xg: wave-private x-gate staging, k-MAJOR layout. Per-wave 1024 floats:
  //   float idx = j*256 + (lane_p*4 ^ 16*(j&1)),   value = pax[0..3][j]  (b128)
  // Producer (write instr j): consecutive lanes -> consecutive 16B slots, each
  // 8-lane octet covers all 8 bank-quads (m134-contiguous pattern, conflict-
  // free). Consumer (step u): ONE b128 read of all 4 gate values at
  //   idx = rho*256 + 64q + 4b + 16*(u ^ (rho&1))
  // (octet {rho 0,1 x b} -> starts {4b} u {16+4b} = 8 quads, conflict-free).
  // Single-buffered safe: group tt+1 pieces live in REGISTERS during group tt;
  // published at iteration-top after group tt's last read (program order).
  __shared__ __align__(16) float xgbuf[8 * 1024];  // 32 KB
  __shared__ float xh_lds[4][T_];
  __shared__ float ag_lds[4][T_];
  __shared__ float wr_s[64], wv_s[64], bg_s[64];
  __shared__ int srcs[E_];
  __shared__ int nsrc, iflag;

  // ---- A: init
  if (tid == 0) { nsrc = 0; iflag = 0; }
  for (int i = tid; i < 2 * 4 * HP_; i += 512) hbuf[i] = 0;
  __syncthreads();

  // ---- B: int64-vs-int32 edge_index probe
  {
    int odd = 0;
    for (int e = tid; e < E_; e += 512) odd |= eidx[2 * e + 1];
    if (odd) atomicOr(&iflag, 1);
  }
  __syncthreads();
  const bool i32 = iflag != 0;

  // ---- C: in-edges for this station; stage small tensors; bias (pre-scaled)
  for (int e = tid; e < E_; e += 512) {
    int se = i32 ? eidx[e] : eidx[2 * e];
    int de = i32 ? eidx[E_ + e] : eidx[2 * E_ + 2 * e];
    if (de == s) { int i = atomicAdd(&nsrc, 1); srcs[i] = se; }
  }
  if (tid < 64) { wr_s[tid] = Wroot[tid]; wv_s[tid] = Wrel[tid]; bg_s[tid] = bgnn[tid]; }
  for (int i = tid; i < 4 * T_; i += 512) {
    int bb = i / T_, t = i % T_;
    xh_lds[bb][t] = dh[((size_t)(bg * 4 + bb) * T_ + t) * NH_ + s];
  }
  floatx4 bias_init[4];
#pragma unroll
  for (int blk = 0; blk < 4; blk++) {
    const float scb = (blk == 2) ? S2_ : NS1_;
#pragma unroll
    for (int r = 0; r < 4; r++) {
      const int nb = blk * 128 + w * 16 + q * 4 + r;
      bias_init[blk][r] = (bih[s * 512 + nb] + bhh[s * 512 + nb]) * scb;
    }
  }
  __syncthreads();

  // ---- D: per-(b,t) graph aggregation (avg ~4 in-edges/station)
  const int ns = nsrc;
  for (int i = tid; i < 4 * T_; i += 512) {
    int bb = i / T_, t = i % T_;
    size_t gb = (size_t)(bg * 4 + bb) * T_ + t;
    float a = 0.f;
    for (int j = 0; j < ns; j++) {
      int sr = srcs[j];
      a += (sr < NH_) ? dh[gb * NH_ + sr] : dm[gb * NM_ + (sr - NH_)];
    }
    ag_lds[bb][t] = a;
  }

  // ---- W: coalesced LDS-staged weight load, THREE fully-unrolled rounds.
  // Gate-scale constants are folded in here (off the recurrent critical path).
  short8 Af[4][6];
  const int nl = w * 16 + cm;  // this lane's gate-row within a 128-block
  // Round 1: all of Wih (512 rows x 64); row = j>>4, gate block = j>>11
  __syncthreads();
  {
    const float* g = Wih + (size_t)s * 512 * 64;
#pragma unroll
    for (int it = 0; it < 16; it++) {
      int j = tid + it * 512;
      float4v v = *(const float4v*)(g + 4 * j);
      const float sc = ((j >> 11) == 2) ? S2_ : NS1_;
      u16* dst = ovl + (j >> 4) * WIH_LP + (j & 15) * 4;
      dst[0] = f2bf(v[0] * sc); dst[1] = f2bf(v[1] * sc);
      dst[2] = f2bf(v[2] * sc); dst[3] = f2bf(v[3] * sc);
    }
  }
  __syncthreads();
#pragma unroll
  for (int blk = 0; blk < 4; blk++)
#pragma unroll
    for (int kk = 0; kk < 2; kk++)
      Af[blk][kk] = *(const short8*)(ovl + (blk * 128 + nl) * WIH_LP + kk * 32 + q * 8);
  __syncthreads();
  // Round 2: Whh rows 0..255 (gate blocks 0,1 -> always -log2e)
  {
    const float* g = Whh + (size_t)s * 512 * 128;
#pragma unroll
    for (int it = 0; it < 16; it++) {
      int j = tid + it * 512;
      float4v v = *(const float4v*)(g + 4 * j);
      u16* dst = ovl + (j >> 5) * WHH_LP + (j & 31) * 4;
      dst[0] = f2bf(v[0] * NS1_); dst[1] = f2bf(v[1] * NS1_);
      dst[2] = f2bf(v[2] * NS1_); dst[3] = f2bf(v[3] * NS1_);
    }
  }
  __syncthreads();
#pragma unroll
  for (int blk = 0; blk < 2; blk++)
#pragma unroll
    for (int kk = 0; kk < 4; kk++)
      Af[blk][2 + kk] = *(const short8*)(ovl + (blk * 128 + nl) * WHH_LP + kk * 32 + q * 8);
  __syncthreads();
  // Round 3: Whh rows 256..511 (block 2 = g -> +2log2e for j<4096, block 3 = o -> -log2e)
  {
    const float* g = Whh + ((size_t)s * 512 + 256) * 128;
#pragma unroll
    for (int it = 0; it < 16; it++) {
      int j = tid + it * 512;
      float4v v = *(const float4v*)(g + 4 * j);
      const float sc = (j < 4096) ? S2_ : NS1_;
      u16* dst = ovl + (j >> 5) * WHH_LP + (j & 31) * 4;
      dst[0] = f2bf(v[0] * sc); dst[1] = f2bf(v[1] * sc);
      dst[2] = f2bf(v[2] * sc); dst[3] = f2bf(v[3] * sc);
    }
  }
  __syncthreads();
#pragma unroll
  for (int blk = 2; blk < 4; blk++)
#pragma unroll
    for (int kk = 0; kk < 4; kk++)
      Af[blk][2 + kk] = *(const short8*)(ovl + ((blk - 2) * 128 + nl) * WHH_LP + kk * 32 + q * 8);
  __syncthreads();

  // ---- E: precompute GNN features into xbuf (= ovl; weights now in registers)
  {
    const int k = tid & 63;
    const int bb = (tid >> 6) & 3;
    const int th = tid >> 8;
    const float wrk = wr_s[k], wvk = wv_s[k], bgk = bg_s[k];
    for (int i = 0; i < T_ / 2; i++) {
      const int t = th * (T_ / 2) + i;
      const float xv = xh_lds[bb][t] * wrk + ag_lds[bb][t] * wvk + bgk;
      ovl[t * (4 * XP_) + bb * XP_ + k] = f2bf(lrelu(xv));
    }
  }
  __syncthreads();

  // ---- xg addressing (loop-invariant)
  const int lane4 = lane * 4;
  float* const xgW = xgbuf + w * 1024;  // + j*256 + (lane4 ^ ((j&1)<<4))
  const float* const xgRb = xgbuf + w * 1024 + rho * 256 + 64 * q + 4 * b;  // + 16*(u^(rho&1))
  const int rxr = (rho & 1) << 4;

  floatx4 zvec;
  zvec[0] = 0.f; zvec[1] = 0.f; zvec[2] = 0.f; zvec[3] = 0.f;

  // ---- prologue: compute x-gate pieces for group 0 into registers (tb = rho)
  floatx4 pax[4];
  {
    short8 Bx0 = *(const short8*)(ovl + rho * (4 * XP_) + b * XP_ + q * 8);
    short8 Bx1 = *(const short8*)(ovl + rho * (4 * XP_) + b * XP_ + 32 + q * 8);
#pragma unroll
    for (int k = 0; k < 4; k++) {
      pax[k] = __builtin_amdgcn_mfma_f32_16x16x32_bf16(Af[k][0], Bx0, bias_init[k], 0, 0, 0);
      pax[k] = __builtin_amdgcn_mfma_f32_16x16x32_bf16(Af[k][1], Bx1, pax[k], 0, 0, 0);
    }
  }

  // ---- recurrent loop. Per group: publish register-held pieces (4 b128,
  // lane-contiguous, conflict-free), then 4 steps. Per step (post-barrier):
  // issue Bh reads + ONE xg b128 read, compute one burst piece (2 MFMAs on Bn
  // regs) filling the ds_read window, then h-MFMA chains (g,i first -> early
  // exp2; then f,o), activation, barrier.
  float c = 0.0f;
  for (int tt = 0; tt < T_ / 4; tt++) {
    // publish group tt's x-gates (computed during group tt-1 / prologue),
    // transposed to k-major in registers
#pragma unroll
    for (int j = 0; j < 4; j++) {
      floatx4 vv;
      vv[0] = pax[0][j]; vv[1] = pax[1][j]; vv[2] = pax[2][j]; vv[3] = pax[3][j];
      *(floatx4*)(xgW + j * 256 + (lane4 ^ ((j & 1) << 4))) = vv;
    }

    short8 Bn0, Bn1;
    {
      const int tbn = min((tt + 1) * 4, T_ - 4) + rho;  // clamp: last group's pieces unused
      Bn0 = *(const short8*)(ovl + tbn * (4 * XP_) + b * XP_ + q * 8);
      Bn1 = *(const short8*)(ovl + tbn * (4 * XP_) + b * XP_ + 32 + q * 8);
    }
#pragma unroll
    for (int u = 0; u < 4; u++) {
      const int p = u & 1, pn = p ^ 1;  // t = tt*4+u -> t&1 == u&1
      short8 Bh[4];
#pragma unroll
      for (int kk = 0; kk < 4; kk++)
        Bh[kk] = *(const short8*)(hbuf + p * (4 * HP_) + b * HP_ + kk * 32 + q * 8);
      // this lane's x+bias gate values for step tt*4+u: one b128
      const floatx4 xgv = *(const floatx4*)(xgRb + ((16 * u) ^ rxr));

      // burst piece blk=u for group tt+1: registers only, fills the read window
      pax[u] = __builtin_amdgcn_mfma_f32_16x16x32_bf16(Af[u][0], Bn0, bias_init[u], 0, 0, 0);
      pax[u] = __builtin_amdgcn_mfma_f32_16x16x32_bf16(Af[u][1], Bn1, pax[u], 0, 0, 0);

      // g (blk2) and i (blk0) chains first -> their transcendentals start early
      floatx4 a2 = __builtin_amdgcn_mfma_f32_16x16x32_bf16(Af[2][2], Bh[0], zvec, 0, 0, 0);
      floatx4 a0 = __builtin_amdgcn_mfma_f32_16x16x32_bf16(Af[0][2], Bh[0], zvec, 0, 0, 0);
#pragma unroll
      for (int kk = 1; kk < 4; kk++) {
        a2 = __builtin_amdgcn_mfma_f32_16x16x32_bf16(Af[2][2 + kk], Bh[kk], a2, 0, 0, 0);
        a0 = __builtin_amdgcn_mfma_f32_16x16x32_bf16(Af[0][2 + kk], Bh[kk], a0, 0, 0, 0);
      }
      const float gg = sel4(a2, rho) + xgv[2];  // = 2*log2e * g
      const float gi = sel4(a0, rho) + xgv[0];  // = -log2e * i
      const float Eg = fexp2(gg);
      const float Ei = fexp2(gi);

      // f (blk1) and o (blk3) chains
      floatx4 a1 = __builtin_amdgcn_mfma_f32_16x16x32_bf16(Af[1][2], Bh[0], zvec, 0, 0, 0);
      floatx4 a3 = __builtin_amdgcn_mfma_f32_16x16x32_bf16(Af[3][2], Bh[0], zvec, 0, 0, 0);
#pragma unroll
      for (int kk = 1; kk < 4; kk++) {
        a1 = __builtin_amdgcn_mfma_f32_16x16x32_bf16(Af[1][2 + kk], Bh[kk], a1, 0, 0, 0);
        a3 = __builtin_amdgcn_mfma_f32_16x16x32_bf16(Af[3][2 + kk], Bh[kk], a3, 0, 0, 0);
      }

      const float tg = 1.0f - 2.0f * frcp(1.0f + Eg);
      const float si = frcp(1.0f + Ei);
      const float gf = sel4(a1, rho) + xgv[1];  // = -log2e * f
      const float go = sel4(a3, rho) + xgv[3];  // = -log2e * o
      const float sf = frcp(1.0f + fexp2(gf));
      c = sf * c + si * tg;
      const float tc = 1.0f - 2.0f * frcp(1.0f + fexp2(S2_ * c));
      const float so = frcp(1.0f + fexp2(go));
      const float hh = so * tc;
      u32 pk;
      asm("v_cvt_pk_bf16_f32 %0, %1, %2" : "=v"(pk) : "v"(hh), "v"(hh));
      hbuf[pn * (4 * HP_) + b * HP_ + w * 16 + q * 4 + rho] = (u16)pk;
      __syncthreads();
    }
  }

  // ---- head: final h is in hbuf[0]
  if (tid < 4 * FUT_) {
    const int bb = tid / FUT_;
    const int f = tid % FUT_;
    float a = blin[f];
#pragma unroll 8
    for (int k = 0; k < HL_; k++) a += b2f(hbuf[bb * HP_ + k]) * Wlin[f * HL_ + k];
    out[((size_t)(bg * 4 + bb) * NH_ + s) * FUT_ + f] = lrelu(a);
  }
}

extern "C" void kernel_launch(void* const* d_in, const int* in_sizes, int n_in,
                              void* d_out, int out_size, void* d_ws, size_t ws_size,
                              hipStream_t stream) {
  const float* dm = (const float*)d_in[0];
  const float* dh = (const float*)d_in[1];
  const int* eidx = (const int*)d_in[2];
  const float* Wroot = (const float*)d_in[3];
  const float* Wrel = (const float*)d_in[4];
  const float* bgnn = (const float*)d_in[5];
  const float* Wih = (const float*)d_in[6];
  const float* Whh = (const float*)d_in[7];
  const float* bih = (const float*)d_in[8];
  const float* bhh = (const float*)d_in[9];
  const float* Wlin = (const float*)d_in[10];
  const float* blin = (const float*)d_in[11];
  float* out = (float*)d_out;

  fused_kernel<<<256, 512, 0, stream>>>(dm, dh, eidx, Wroot, Wrel, bgnn, Wih, Whh,
                                        bih, bhh, Wlin, blin, out);
}